// Round 3
// baseline (193.085 us; speedup 1.0000x reference)
//
#include <hip/hip_runtime.h>

// Problem: B=4,S=4096,D=1024,H=16,HID=ATT=64
//   qkv = x @ [Wq|Wk|Wv] + bias       (16384 x 1024) @ (1024 x 3072)
//   per token: scores(16x16) = q k^T / 8 over HID=64; softmax over heads; ctx = P V
// R3: GEMM -> 4-phase-per-K-tile deep pipeline (T3+T4+T5): 256x256 tile, BK=64 as
//     4 k-slices of 16, mfma_f32_32x32x16_bf16, 2-dbuf LDS (128 KiB), 1 stage issue
//     per phase, vmcnt(6) once per tile, setprio around MFMA cluster, bank-conflict-
//     free k-slice LDS layout (swizzled global source, linear gload_lds dest),
//     64B-coalesced C-write (fixes 1.8x write amplification).

#define AS1 __attribute__((address_space(1)))
#define AS3 __attribute__((address_space(3)))

typedef __bf16 bf16x8 __attribute__((ext_vector_type(8)));
typedef float f32x4 __attribute__((ext_vector_type(4)));
typedef float f32x16 __attribute__((ext_vector_type(16)));
typedef unsigned short u16x8 __attribute__((ext_vector_type(8)));

static constexpr int MTOK = 16384;   // B*S tokens
static constexpr int N3   = 3072;    // 3*H*HID
static constexpr int KD   = 1024;    // D
static constexpr int NT   = KD / 64; // 16 K-tiles of 64

__device__ __forceinline__ unsigned short f2bf(float f) {
  unsigned u = __float_as_uint(f);
  unsigned r = u + 0x7FFFu + ((u >> 16) & 1u);   // round-to-nearest-even
  return (unsigned short)(r >> 16);
}
__device__ __forceinline__ float bf2f(unsigned short s) {
  return __uint_as_float(((unsigned)s) << 16);
}

__device__ __forceinline__ void gload_lds16(const void* g, void* lds_uniform) {
  __builtin_amdgcn_global_load_lds((const AS1 void*)g, (AS3 void*)lds_uniform, 16, 0, 0);
}

// ---------------- kernel 1: x f32 -> bf16 ----------------
__global__ __launch_bounds__(256) void cvt_x_kernel(const float* __restrict__ x,
                                                    unsigned short* __restrict__ xb) {
  int i = blockIdx.x * 256 + threadIdx.x;      // 8 elements per thread, exact grid
  const float4* p = (const float4*)x;
  float4 a = p[2 * i], b = p[2 * i + 1];
  u16x8 o;
  o[0] = f2bf(a.x); o[1] = f2bf(a.y); o[2] = f2bf(a.z); o[3] = f2bf(a.w);
  o[4] = f2bf(b.x); o[5] = f2bf(b.y); o[6] = f2bf(b.z); o[7] = f2bf(b.w);
  *((u16x8*)xb + i) = o;
}

// ------- kernel 2: W (K x N, f32) -> WT (N x K, bf16), bias concat -------
__global__ __launch_bounds__(256) void prep_w_kernel(const float* __restrict__ Wq,
                                                     const float* __restrict__ Wk,
                                                     const float* __restrict__ Wv,
                                                     const float* __restrict__ bq,
                                                     const float* __restrict__ bk,
                                                     const float* __restrict__ bv,
                                                     unsigned short* __restrict__ WT,
                                                     float* __restrict__ bcat) {
  __shared__ float tile[32][33];
  int kt = blockIdx.x * 32;          // k tile (0..1023)
  int nt = blockIdx.y * 32;          // global n tile (0..3071)
  const float* W; const float* bias; int nb;
  if (nt < 1024)      { W = Wq; bias = bq; nb = nt; }
  else if (nt < 2048) { W = Wk; bias = bk; nb = nt - 1024; }
  else                { W = Wv; bias = bv; nb = nt - 2048; }
  int tx = threadIdx.x & 31, ty = threadIdx.x >> 5;  // ty 0..7
#pragma unroll
  for (int it = 0; it < 4; ++it) {
    int kk = it * 8 + ty;
    tile[kk][tx] = W[(size_t)(kt + kk) * 1024 + nb + tx];
  }
  __syncthreads();
#pragma unroll
  for (int it = 0; it < 4; ++it) {
    int nn = it * 8 + ty;
    WT[(size_t)(nt + nn) * 1024 + kt + tx] = f2bf(tile[tx][nn]);
  }
  if (blockIdx.x == 0 && threadIdx.x < 32)
    bcat[nt + threadIdx.x] = bias[nb + threadIdx.x];
}

// ---------------- kernel 3: GEMM qkv = xb @ WT^T + bias (bf16 out) ----------------
// 256x256 tile, 512 threads = 8 waves (2M x 4N), per-wave C = 128x64 via 4x2
// frags of v_mfma_f32_32x32x16_bf16.
// LDS: 2 buffers x 4 k-slices; slice = A[256][16] (8KB) + B[256][16] (8KB).
//   Within a slice, 16B chunk of (row, khalf h) lives at byte
//   (row>>2)*128 + ((h ^ ((row>>2)&1))*4 + (row&3))*16  -> every 8-lane b128 group
//   spans all 32 banks. gload_lds dest is LINEAR (thread t -> slice + t*16B);
//   the global SOURCE is pre-permuted with the inverse mapping (rule #21).
// Schedule per K-tile t (4 phases, slice p read at phase p):
//   p0: vmcnt(6); barrier; ds_read; lgkm0; barrier; stage(t+1,s3); 8 MFMA
//   p>0:                    ds_read; lgkm0; barrier; stage(t+2,s p-1); 8 MFMA
// WAR: every stage issue is after the barrier retiring its destination's last read.
// RAW: vmcnt(6) keeps exactly the newest 3 stages = next tile's s0..s2; all of
//      tile t has landed. Tail: NT-2 stages only (NT-1,s3); NT-1 uses vmcnt(0).
__global__ __launch_bounds__(512, 2) void gemm_qkv_kernel(const unsigned short* __restrict__ A,
                                                          const unsigned short* __restrict__ Bt,
                                                          const float* __restrict__ bias,
                                                          unsigned short* __restrict__ C) {
  __shared__ __align__(16) unsigned short lds[65536];  // 128 KiB
  const int tid  = threadIdx.x;
  const int lane = tid & 63;
  const int wave = tid >> 6;
  const int wm = wave >> 2, wn = wave & 3;   // 2x4 wave grid, per-wave 128x64
  const int m0 = blockIdx.x * 256;
  const int n0 = blockIdx.y * 256;

  // staging: thread t owns linear 16B slot t of the A-part (and B-part) of a slice.
  // decode slot -> logical (row, khalf) under the swizzle:
  const int sp_ = tid >> 3;                  // period (row group of 4)
  const int srow = sp_ * 4 + (tid & 3);      // 0..255
  const int sh   = ((tid >> 2) & 1) ^ (sp_ & 1);  // k-half 0/1
  const size_t asrc = (size_t)(m0 + srow) * KD + sh * 8;
  const size_t bsrc = (size_t)(n0 + srow) * KD + sh * 8;

  // fragment ds_read offsets (elements within a slice)
  int aoff[4], boff[2];
#pragma unroll
  for (int m = 0; m < 4; ++m) {
    int row = wm * 128 + m * 32 + (lane & 31);
    int p = row >> 2;
    aoff[m] = (p * 128 + (((lane >> 5) ^ (p & 1)) * 4 + (row & 3)) * 16) >> 1;
  }
#pragma unroll
  for (int n = 0; n < 2; ++n) {
    int row = wn * 64 + n * 32 + (lane & 31);
    int p = row >> 2;
    boff[n] = 4096 + ((p * 128 + (((lane >> 5) ^ (p & 1)) * 4 + (row & 3)) * 16) >> 1);
  }

  f32x16 acc[4][2] = {};

#define STAGE(T, P)                                                            \
  do {                                                                         \
    unsigned short* dst = lds + ((T) & 1) * 32768 + (P) * 8192 + tid * 8;      \
    const int kk = (T) * 64 + (P) * 16;                                        \
    gload_lds16(A  + asrc + kk, dst);                                          \
    gload_lds16(Bt + bsrc + kk, dst + 4096);                                   \
  } while (0)

#define PHASE(T, P, DOSTAGE, ST, SSL)                                          \
  do {                                                                         \
    const unsigned short* bufp = lds + ((T) & 1) * 32768 + (P) * 8192;         \
    bf16x8 af[4], bfr[2];                                                      \
    _Pragma("unroll") for (int m = 0; m < 4; ++m)                              \
      af[m] = *(const bf16x8*)(bufp + aoff[m]);                                \
    _Pragma("unroll") for (int n = 0; n < 2; ++n)                              \
      bfr[n] = *(const bf16x8*)(bufp + boff[n]);                               \
    asm volatile("s_waitcnt lgkmcnt(0)" ::: "memory");                         \
    __builtin_amdgcn_sched_barrier(0);                                         \
    __builtin_amdgcn_s_barrier();                                              \
    if (DOSTAGE) { STAGE(ST, SSL); }                                           \
    __builtin_amdgcn_sched_barrier(0);                                         \
    __builtin_amdgcn_s_setprio(1);                                             \
    _Pragma("unroll") for (int m = 0; m < 4; ++m)                              \
      _Pragma("unroll") for (int n = 0; n < 2; ++n)                            \
        acc[m][n] = __builtin_amdgcn_mfma_f32_32x32x16_bf16(af[m], bfr[n],     \
                                                            acc[m][n], 0, 0, 0);\
    __builtin_amdgcn_s_setprio(0);                                             \
  } while (0)

  // prologue: tile0 all 4 slices, tile1 slices 0..2  (7 stages = 14 loads in flight)
  STAGE(0, 0); STAGE(0, 1); STAGE(0, 2); STAGE(0, 3);
  STAGE(1, 0); STAGE(1, 1); STAGE(1, 2);

#pragma unroll 1
  for (int t = 0; t < NT - 2; ++t) {
    asm volatile("s_waitcnt vmcnt(6)" ::: "memory");
    __builtin_amdgcn_s_barrier();
    PHASE(t, 0, true, t + 1, 3);
    PHASE(t, 1, true, t + 2, 0);
    PHASE(t, 2, true, t + 2, 1);
    PHASE(t, 3, true, t + 2, 2);
  }
  // t = NT-2: only (NT-1, s3) remains to stage
  asm volatile("s_waitcnt vmcnt(6)" ::: "memory");
  __builtin_amdgcn_s_barrier();
  PHASE(NT - 2, 0, true, NT - 1, 3);
  PHASE(NT - 2, 1, false, 0, 0);
  PHASE(NT - 2, 2, false, 0, 0);
  PHASE(NT - 2, 3, false, 0, 0);
  // t = NT-1: everything must be in
  asm volatile("s_waitcnt vmcnt(0)" ::: "memory");
  __builtin_amdgcn_s_barrier();
  PHASE(NT - 1, 0, false, 0, 0);
  PHASE(NT - 1, 1, false, 0, 0);
  PHASE(NT - 1, 2, false, 0, 0);
  PHASE(NT - 1, 3, false, 0, 0);
#undef STAGE
#undef PHASE

  // epilogue: 32x32 C/D layout: col = lane&31, row = (r&3) + 8*(r>>2) + 4*(lane>>5)
  // -> each store: 32 lanes x 2B = 64B full sector.
#pragma unroll
  for (int n = 0; n < 2; ++n) {
    int col = n0 + wn * 64 + n * 32 + (lane & 31);
    float bvv = bias[col];
#pragma unroll
    for (int m = 0; m < 4; ++m) {
      int rowb = m0 + wm * 128 + m * 32 + 4 * (lane >> 5);
#pragma unroll
      for (int r = 0; r < 16; ++r) {
        int row = rowb + (r & 3) + 8 * (r >> 2);
        C[(size_t)row * N3 + col] = f2bf(acc[m][n][r] + bvv);
      }
    }
  }
}

// ---------------- kernel 4: per-token head attention ----------------
// 1 wave per token; scores via 2 MFMAs straight from global; softmax across 16-lane
// groups; P -> LDS; PV on VALU; coalesced f32 out.
__global__ __launch_bounds__(256) void attn_kernel(const unsigned short* __restrict__ qkv,
                                                   float* __restrict__ out) {
  __shared__ float p_lds[4][16][17];
  const int tid = threadIdx.x;
  const int lane = tid & 63;
  const int w = tid >> 6;
  const size_t token = (size_t)blockIdx.x * 4 + w;
  const unsigned short* rowp = qkv + token * N3;
  const int head = lane & 15;     // A-frag row (q head) and B-frag col (k head)
  const int chunk = lane >> 4;    // k-dim subchunk

  const int o = head * 64 + chunk * 8;
  bf16x8 q0 = *(const bf16x8*)(rowp + o);
  bf16x8 q1 = *(const bf16x8*)(rowp + o + 32);
  bf16x8 k0 = *(const bf16x8*)(rowp + 1024 + o);
  bf16x8 k1 = *(const bf16x8*)(rowp + 1024 + o + 32);
  f32x4 c = {0.f, 0.f, 0.f, 0.f};
  c = __builtin_amdgcn_mfma_f32_16x16x32_bf16(q0, k0, c, 0, 0, 0);
  c = __builtin_amdgcn_mfma_f32_16x16x32_bf16(q1, k1, c, 0, 0, 0);
  // c[r] = scores[row = chunk*4+r][col = head]

#pragma unroll
  for (int r = 0; r < 4; ++r) {
    float s = c[r] * 0.125f;
    float m = s;
#pragma unroll
    for (int off = 1; off < 16; off <<= 1) m = fmaxf(m, __shfl_xor(m, off, 64));
    float e = __expf(s - m);
    float sum = e;
#pragma unroll
    for (int off = 1; off < 16; off <<= 1) sum += __shfl_xor(sum, off, 64);
    p_lds[w][chunk * 4 + r][head] = e / sum;
  }
  __syncthreads();

  // PV: lane owns (i = lane>>2, a-block = lane&3): 16 f32 outputs
  const int i = lane >> 2;
  const int ab = lane & 3;
  const unsigned short* vbase = rowp + 2048 + ab * 16;
  float accv[16];
#pragma unroll
  for (int cc = 0; cc < 16; ++cc) accv[cc] = 0.f;
#pragma unroll
  for (int j = 0; j < 16; ++j) {
    float pij = p_lds[w][i][j];
    u16x8 v0 = *(const u16x8*)(vbase + j * 64);
    u16x8 v1 = *(const u16x8*)(vbase + j * 64 + 8);
#pragma unroll
    for (int cc = 0; cc < 8; ++cc) accv[cc] += pij * bf2f(v0[cc]);
#pragma unroll
    for (int cc = 0; cc < 8; ++cc) accv[8 + cc] += pij * bf2f(v1[cc]);
  }
  float* op = out + token * 1024 + i * 64 + ab * 16;
#pragma unroll
  for (int cc = 0; cc < 16; cc += 4) {
    f32x4 v = {accv[cc], accv[cc + 1], accv[cc + 2], accv[cc + 3]};
    *(f32x4*)(op + cc) = v;
  }
}

extern "C" void kernel_launch(void* const* d_in, const int* in_sizes, int n_in,
                              void* d_out, int out_size, void* d_ws, size_t ws_size,
                              hipStream_t stream) {
  const float* x  = (const float*)d_in[0];
  const float* Wq = (const float*)d_in[1];
  const float* bq = (const float*)d_in[2];
  const float* Wk = (const float*)d_in[3];
  const float* bk = (const float*)d_in[4];
  const float* Wv = (const float*)d_in[5];
  const float* bv = (const float*)d_in[6];
  float* out = (float*)d_out;

  char* ws = (char*)d_ws;
  unsigned short* xb   = (unsigned short*)ws;               // 16384*1024*2 = 33,554,432
  unsigned short* WT   = (unsigned short*)(ws + 33554432);  //  3072*1024*2 =  6,291,456
  float*          bcat = (float*)(ws + 39845888);           //  3072*4      =     12,288
  unsigned short* qkv  = (unsigned short*)(ws + 39858176);  // 16384*3072*2 = 100,663,296

  cvt_x_kernel<<<dim3((MTOK * KD / 8) / 256), 256, 0, stream>>>(x, xb);
  prep_w_kernel<<<dim3(32, 96), 256, 0, stream>>>(Wq, Wk, Wv, bq, bk, bv, WT, bcat);
  gemm_qkv_kernel<<<dim3(MTOK / 256, N3 / 256), 512, 0, stream>>>(xb, WT, bcat, qkv);
  attn_kernel<<<dim3(MTOK / 4), 256, 0, stream>>>(qkv, out);
}

// Round 4
// 171.870 us; speedup vs baseline: 1.1234x; 1.1234x over previous
//
#include <hip/hip_runtime.h>

// Problem: B=4,S=4096,D=1024,H=16,HID=ATT=64
//   qkv = x @ [Wq|Wk|Wv] + bias       (16384 x 1024) @ (1024 x 3072)
//   per token: scores(16x16) = q k^T / 8 over HID=64; softmax over heads; ctx = P V
// R4: GEMM schedule fix: 2 phases per BK=64 tile (32-k slices), lgkmcnt(0) AFTER the
//     per-phase barrier (cross-wave LDS/MFMA overlap — m201 ordering), R2's proven
//     zero-conflict LDS layout per slice, one barrier per phase, vmcnt(8) counted
//     pipeline, setprio around the 16-MFMA cluster, 64B-coalesced C-write.

#define AS1 __attribute__((address_space(1)))
#define AS3 __attribute__((address_space(3)))

typedef __bf16 bf16x8 __attribute__((ext_vector_type(8)));
typedef float f32x4 __attribute__((ext_vector_type(4)));
typedef float f32x16 __attribute__((ext_vector_type(16)));
typedef unsigned short u16x8 __attribute__((ext_vector_type(8)));

static constexpr int MTOK = 16384;   // B*S tokens
static constexpr int N3   = 3072;    // 3*H*HID
static constexpr int KD   = 1024;    // D
static constexpr int NT   = KD / 64; // 16 K-tiles of 64

__device__ __forceinline__ unsigned short f2bf(float f) {
  unsigned u = __float_as_uint(f);
  unsigned r = u + 0x7FFFu + ((u >> 16) & 1u);   // round-to-nearest-even
  return (unsigned short)(r >> 16);
}
__device__ __forceinline__ float bf2f(unsigned short s) {
  return __uint_as_float(((unsigned)s) << 16);
}

__device__ __forceinline__ void gload_lds16(const void* g, void* lds_uniform) {
  __builtin_amdgcn_global_load_lds((const AS1 void*)g, (AS3 void*)lds_uniform, 16, 0, 0);
}

// ---------------- kernel 1: x f32 -> bf16 ----------------
__global__ __launch_bounds__(256) void cvt_x_kernel(const float* __restrict__ x,
                                                    unsigned short* __restrict__ xb) {
  int i = blockIdx.x * 256 + threadIdx.x;      // 8 elements per thread, exact grid
  const float4* p = (const float4*)x;
  float4 a = p[2 * i], b = p[2 * i + 1];
  u16x8 o;
  o[0] = f2bf(a.x); o[1] = f2bf(a.y); o[2] = f2bf(a.z); o[3] = f2bf(a.w);
  o[4] = f2bf(b.x); o[5] = f2bf(b.y); o[6] = f2bf(b.z); o[7] = f2bf(b.w);
  *((u16x8*)xb + i) = o;
}

// ------- kernel 2: W (K x N, f32) -> WT (N x K, bf16), bias concat -------
__global__ __launch_bounds__(256) void prep_w_kernel(const float* __restrict__ Wq,
                                                     const float* __restrict__ Wk,
                                                     const float* __restrict__ Wv,
                                                     const float* __restrict__ bq,
                                                     const float* __restrict__ bk,
                                                     const float* __restrict__ bv,
                                                     unsigned short* __restrict__ WT,
                                                     float* __restrict__ bcat) {
  __shared__ float tile[32][33];
  int kt = blockIdx.x * 32;          // k tile (0..1023)
  int nt = blockIdx.y * 32;          // global n tile (0..3071)
  const float* W; const float* bias; int nb;
  if (nt < 1024)      { W = Wq; bias = bq; nb = nt; }
  else if (nt < 2048) { W = Wk; bias = bk; nb = nt - 1024; }
  else                { W = Wv; bias = bv; nb = nt - 2048; }
  int tx = threadIdx.x & 31, ty = threadIdx.x >> 5;  // ty 0..7
#pragma unroll
  for (int it = 0; it < 4; ++it) {
    int kk = it * 8 + ty;
    tile[kk][tx] = W[(size_t)(kt + kk) * 1024 + nb + tx];
  }
  __syncthreads();
#pragma unroll
  for (int it = 0; it < 4; ++it) {
    int nn = it * 8 + ty;
    WT[(size_t)(nt + nn) * 1024 + kt + tx] = f2bf(tile[tx][nn]);
  }
  if (blockIdx.x == 0 && threadIdx.x < 32)
    bcat[nt + threadIdx.x] = bias[nb + threadIdx.x];
}

// ---------------- kernel 3: GEMM qkv = xb @ WT^T + bias (bf16 out) ----------------
// 256x256 tile, 512 threads = 8 waves (2M x 4N), per-wave C = 128x64 via 4x2 frags
// of v_mfma_f32_32x32x16_bf16, BK=64 as 2 slices of 32-k.
// LDS: 2 buffers x 2 slices x (A[256][32] | B[256][32]) = 128 KiB.
//   Slice layout (R2-proven, 0 conflicts): 16B chunk c of row r at byte
//   r*64 + (c ^ ((r>>1)&3))*16. gload_lds dest LINEAR (thread t -> t*16B);
//   global SOURCE pre-permuted with the same involution (rule #21).
// Phase (t,s): vmcnt(N); s_barrier; issue 12 ds_reads(t,s); issue 4-gload stage;
//   lgkmcnt(0); sched_barrier; setprio(1); 16 MFMA; setprio(0).
//   lgkm AFTER barrier => early waves MFMA while late waves' reads are serviced.
// Ledger: stage(t+1,s1)@(t,p0), stage(t+2,s0)@(t,p1). WAR: any stage target's last
//   reads were lgkm0'd before the preceding barrier. RAW: steady vmcnt(8) keeps the
//   2 newest slice-stages (8 loads) in flight; tail peels 8/8/4/0.
__global__ __launch_bounds__(512, 2) void gemm_qkv_kernel(const unsigned short* __restrict__ A,
                                                          const unsigned short* __restrict__ Bt,
                                                          const float* __restrict__ bias,
                                                          unsigned short* __restrict__ C) {
  __shared__ __align__(16) unsigned short lds[65536];  // 128 KiB
  const int tid  = threadIdx.x;
  const int lane = tid & 63;
  const int wave = tid >> 6;
  const int wm = wave >> 2, wn = wave & 3;   // 2x4 wave grid, per-wave 128x64
  const int m0 = blockIdx.x * 256;
  const int n0 = blockIdx.y * 256;

  // staging decode: thread owns linear 16B chunks j=tid and j=tid+512 of each part.
  // chunk j: row=j>>2, phys slot=j&3, logical k-chunk c = (j&3) ^ ((row>>1)&3).
  const int srow = tid >> 2;                               // 0..127
  const int sc   = ((tid & 3) ^ ((srow >> 1) & 3)) * 8;    // logical k-offset (elems)
  const size_t asrc0 = (size_t)(m0 + srow) * KD + sc;
  const size_t asrc1 = (size_t)(m0 + 128 + srow) * KD + sc;   // (r+128): same swizzle bits
  const size_t bsrc0 = (size_t)(n0 + srow) * KD + sc;
  const size_t bsrc1 = (size_t)(n0 + 128 + srow) * KD + sc;

  // fragment ds_read offsets (elements within a slice); ks = k-substep (16-k) 0/1
  int aoff[4][2], boff[2][2];
#pragma unroll
  for (int m = 0; m < 4; ++m) {
    int row = wm * 128 + m * 32 + (lane & 31);
#pragma unroll
    for (int ks = 0; ks < 2; ++ks) {
      int pc = (ks * 2 + (lane >> 5)) ^ ((row >> 1) & 3);
      aoff[m][ks] = row * 32 + pc * 8;
    }
  }
#pragma unroll
  for (int n = 0; n < 2; ++n) {
    int row = wn * 64 + n * 32 + (lane & 31);
#pragma unroll
    for (int ks = 0; ks < 2; ++ks) {
      int pc = (ks * 2 + (lane >> 5)) ^ ((row >> 1) & 3);
      boff[n][ks] = 8192 + row * 32 + pc * 8;
    }
  }

  f32x16 acc[4][2] = {};

#define STAGE(T, S)                                                            \
  do {                                                                         \
    unsigned short* dst = lds + ((T) & 1) * 32768 + (S) * 16384 + tid * 8;     \
    const int kk = (T) * 64 + (S) * 32;                                        \
    gload_lds16(A  + asrc0 + kk, dst);                                         \
    gload_lds16(A  + asrc1 + kk, dst + 4096);                                  \
    gload_lds16(Bt + bsrc0 + kk, dst + 8192);                                  \
    gload_lds16(Bt + bsrc1 + kk, dst + 12288);                                 \
  } while (0)

#define PHASE(T, S, DOSTAGE, ST, SS)                                           \
  do {                                                                         \
    const unsigned short* bufp = lds + ((T) & 1) * 32768 + (S) * 16384;        \
    bf16x8 af[4][2], bfr[2][2];                                                \
    _Pragma("unroll") for (int m = 0; m < 4; ++m)                              \
      _Pragma("unroll") for (int ks = 0; ks < 2; ++ks)                         \
        af[m][ks] = *(const bf16x8*)(bufp + aoff[m][ks]);                      \
    _Pragma("unroll") for (int n = 0; n < 2; ++n)                              \
      _Pragma("unroll") for (int ks = 0; ks < 2; ++ks)                         \
        bfr[n][ks] = *(const bf16x8*)(bufp + boff[n][ks]);                     \
    if (DOSTAGE) { STAGE(ST, SS); }                                            \
    asm volatile("s_waitcnt lgkmcnt(0)" ::: "memory");                         \
    __builtin_amdgcn_sched_barrier(0);                                         \
    __builtin_amdgcn_s_setprio(1);                                             \
    _Pragma("unroll") for (int ks = 0; ks < 2; ++ks)                           \
      _Pragma("unroll") for (int m = 0; m < 4; ++m)                            \
        _Pragma("unroll") for (int n = 0; n < 2; ++n)                          \
          acc[m][n] = __builtin_amdgcn_mfma_f32_32x32x16_bf16(af[m][ks],       \
                          bfr[n][ks], acc[m][n], 0, 0, 0);                     \
    __builtin_amdgcn_s_setprio(0);                                             \
  } while (0)

#define SYNC(VM)                                                               \
  do {                                                                         \
    asm volatile("s_waitcnt vmcnt(" #VM ")" ::: "memory");                     \
    __builtin_amdgcn_s_barrier();                                              \
    __builtin_amdgcn_sched_barrier(0);                                         \
  } while (0)

  // prologue: stage (0,s0), (0,s1), (1,s0) -> 12 loads in flight
  STAGE(0, 0); STAGE(0, 1); STAGE(1, 0);

#pragma unroll 1
  for (int t = 0; t < NT - 2; ++t) {
    SYNC(8); PHASE(t, 0, true, t + 1, 1);
    SYNC(8); PHASE(t, 1, true, t + 2, 0);
  }
  // t = NT-2: second stage target (NT,s0) doesn't exist
  SYNC(8); PHASE(NT - 2, 0, true, NT - 1, 1);
  SYNC(8); PHASE(NT - 2, 1, false, 0, 0);
  // t = NT-1: nothing left to stage
  SYNC(4); PHASE(NT - 1, 0, false, 0, 0);
  SYNC(0); PHASE(NT - 1, 1, false, 0, 0);
#undef STAGE
#undef PHASE
#undef SYNC

  // epilogue: 32x32 C/D layout: col = lane&31, row = (r&3) + 8*(r>>2) + 4*(lane>>5)
  // -> each store: 32 lanes x 2B = 64B full sector.
#pragma unroll
  for (int n = 0; n < 2; ++n) {
    int col = n0 + wn * 64 + n * 32 + (lane & 31);
    float bvv = bias[col];
#pragma unroll
    for (int m = 0; m < 4; ++m) {
      int rowb = m0 + wm * 128 + m * 32 + 4 * (lane >> 5);
#pragma unroll
      for (int r = 0; r < 16; ++r) {
        int row = rowb + (r & 3) + 8 * (r >> 2);
        C[(size_t)row * N3 + col] = f2bf(acc[m][n][r] + bvv);
      }
    }
  }
}

// ---------------- kernel 4: per-token head attention ----------------
// 1 wave per token; scores via 2 MFMAs straight from global; softmax across 16-lane
// groups; P -> LDS; PV on VALU; coalesced f32 out.
__global__ __launch_bounds__(256) void attn_kernel(const unsigned short* __restrict__ qkv,
                                                   float* __restrict__ out) {
  __shared__ float p_lds[4][16][17];
  const int tid = threadIdx.x;
  const int lane = tid & 63;
  const int w = tid >> 6;
  const size_t token = (size_t)blockIdx.x * 4 + w;
  const unsigned short* rowp = qkv + token * N3;
  const int head = lane & 15;     // A-frag row (q head) and B-frag col (k head)
  const int chunk = lane >> 4;    // k-dim subchunk

  const int o = head * 64 + chunk * 8;
  bf16x8 q0 = *(const bf16x8*)(rowp + o);
  bf16x8 q1 = *(const bf16x8*)(rowp + o + 32);
  bf16x8 k0 = *(const bf16x8*)(rowp + 1024 + o);
  bf16x8 k1 = *(const bf16x8*)(rowp + 1024 + o + 32);
  f32x4 c = {0.f, 0.f, 0.f, 0.f};
  c = __builtin_amdgcn_mfma_f32_16x16x32_bf16(q0, k0, c, 0, 0, 0);
  c = __builtin_amdgcn_mfma_f32_16x16x32_bf16(q1, k1, c, 0, 0, 0);
  // c[r] = scores[row = chunk*4+r][col = head]

#pragma unroll
  for (int r = 0; r < 4; ++r) {
    float s = c[r] * 0.125f;
    float m = s;
#pragma unroll
    for (int off = 1; off < 16; off <<= 1) m = fmaxf(m, __shfl_xor(m, off, 64));
    float e = __expf(s - m);
    float sum = e;
#pragma unroll
    for (int off = 1; off < 16; off <<= 1) sum += __shfl_xor(sum, off, 64);
    p_lds[w][chunk * 4 + r][head] = e / sum;
  }
  __syncthreads();

  // PV: lane owns (i = lane>>2, a-block = lane&3): 16 f32 outputs
  const int i = lane >> 2;
  const int ab = lane & 3;
  const unsigned short* vbase = rowp + 2048 + ab * 16;
  float accv[16];
#pragma unroll
  for (int cc = 0; cc < 16; ++cc) accv[cc] = 0.f;
#pragma unroll
  for (int j = 0; j < 16; ++j) {
    float pij = p_lds[w][i][j];
    u16x8 v0 = *(const u16x8*)(vbase + j * 64);
    u16x8 v1 = *(const u16x8*)(vbase + j * 64 + 8);
#pragma unroll
    for (int cc = 0; cc < 8; ++cc) accv[cc] += pij * bf2f(v0[cc]);
#pragma unroll
    for (int cc = 0; cc < 8; ++cc) accv[8 + cc] += pij * bf2f(v1[cc]);
  }
  float* op = out + token * 1024 + i * 64 + ab * 16;
#pragma unroll
  for (int cc = 0; cc < 16; cc += 4) {
    f32x4 v = {accv[cc], accv[cc + 1], accv[cc + 2], accv[cc + 3]};
    *(f32x4*)(op + cc) = v;
  }
}

extern "C" void kernel_launch(void* const* d_in, const int* in_sizes, int n_in,
                              void* d_out, int out_size, void* d_ws, size_t ws_size,
                              hipStream_t stream) {
  const float* x  = (const float*)d_in[0];
  const float* Wq = (const float*)d_in[1];
  const float* bq = (const float*)d_in[2];
  const float* Wk = (const float*)d_in[3];
  const float* bk = (const float*)d_in[4];
  const float* Wv = (const float*)d_in[5];
  const float* bv = (const float*)d_in[6];
  float* out = (float*)d_out;

  char* ws = (char*)d_ws;
  unsigned short* xb   = (unsigned short*)ws;               // 16384*1024*2 = 33,554,432
  unsigned short* WT   = (unsigned short*)(ws + 33554432);  //  3072*1024*2 =  6,291,456
  float*          bcat = (float*)(ws + 39845888);           //  3072*4      =     12,288
  unsigned short* qkv  = (unsigned short*)(ws + 39858176);  // 16384*3072*2 = 100,663,296

  cvt_x_kernel<<<dim3((MTOK * KD / 8) / 256), 256, 0, stream>>>(x, xb);
  prep_w_kernel<<<dim3(32, 96), 256, 0, stream>>>(Wq, Wk, Wv, bq, bk, bv, WT, bcat);
  gemm_qkv_kernel<<<dim3(MTOK / 256, N3 / 256), 512, 0, stream>>>(xb, WT, bcat, qkv);
  attn_kernel<<<dim3(MTOK / 4), 256, 0, stream>>>(qkv, out);
}